// Round 7
// baseline (954.479 us; speedup 1.0000x reference)
//
#include <hip/hip_runtime.h>
#include <hip/hip_bf16.h>
#include <cstdint>

// Problem constants
#define SDIM   2048
#define DDIM   1024
#define VDIM   50257
#define VPAD   50432          // 197 * 256
#define NROWS  4094           // B*(S-1) = 2*2047
#define MPAD   4096
#define NTM    16             // M tiles of 256
#define NTN    197            // N tiles of 256
#define NCHUNK (NTN * 4)      // 788 column chunks of 64
#define NKT    16             // 1024 / 64
#define IGNORE_IDX (-100)
// Finite "minus infinity": avoids exp(-inf - -inf) = NaN on all-padding chunks.
#define NEGBIG (-3.0e38f)
#define SLICE_SH 8192         // one K-slice: 256 rows x 32 cols bf16 = 16KB

typedef __bf16 bf16x8 __attribute__((ext_vector_type(8)));
typedef float  f32x4  __attribute__((ext_vector_type(4)));

__device__ static inline unsigned short f2bf(float f) {
    union { float f; uint32_t u; } v; v.f = f;
    uint32_t u = v.u;
    return (unsigned short)((u + 0x7FFFu + ((u >> 16) & 1u)) >> 16);  // RNE
}

// global -> LDS direct (16B per lane). LDS dest must be wave-uniform base + lane*16.
__device__ static inline void gload_lds16(const void* g, void* l) {
    __builtin_amdgcn_global_load_lds(
        (const __attribute__((address_space(1))) unsigned int*)(g),
        (__attribute__((address_space(3))) unsigned int*)(l),
        16, 0, 0);
}

// ---------------- convert W (fp32 [V,D]) -> bf16 [VPAD,D], pad rows zero ----
__global__ __launch_bounds__(256) void k_convert_W(const float* __restrict__ W,
                                                   unsigned short* __restrict__ Wb,
                                                   float* __restrict__ acc) {
    if (blockIdx.x == 0 && threadIdx.x < 2) acc[threadIdx.x] = 0.f;  // zero accumulators
    const int row = blockIdx.x;            // grid = VPAD
    const int c4  = threadIdx.x << 2;      // 256 threads * 4 = 1024 = D
    ushort4 o;
    if (row < VDIM) {
        const float4 f = *(const float4*)(W + (size_t)row * DDIM + c4);
        o.x = f2bf(f.x); o.y = f2bf(f.y); o.z = f2bf(f.z); o.w = f2bf(f.w);
    } else {
        o.x = o.y = o.z = o.w = 0;
    }
    *(ushort4*)(Wb + (size_t)row * DDIM + c4) = o;
}

// --------- pack shifted embeddings: row r<4094 -> emb[b= r/2047, s= r%2047] ---
__global__ __launch_bounds__(256) void k_convert_A(const float* __restrict__ emb,
                                                   unsigned short* __restrict__ Ab) {
    const int row = blockIdx.x;            // grid = MPAD
    const int c4  = threadIdx.x << 2;
    ushort4 o; o.x = o.y = o.z = o.w = 0;
    if (row < NROWS) {
        const int bb = row / 2047;
        const int s  = row - bb * 2047;
        const float4 f = *(const float4*)(emb + ((size_t)bb * SDIM + s) * DDIM + c4);
        o.x = f2bf(f.x); o.y = f2bf(f.y); o.z = f2bf(f.z); o.w = f2bf(f.w);
    }
    *(ushort4*)(Ab + (size_t)row * DDIM + c4) = o;
}

// ---------------- GEMM 256x256 tile, BK=64, 8 waves, m201-style 8-phase -----
// LDS: per matrix, [2 bufs][2 K-slices][256 rows][32 cols] bf16; tile t -> buf t&1.
// Slice layout: [128 lines][8 chunks(16B)]; chunk p at line L holds row=2L+(p>>2),
// col-slot cs=(p&3)^(L&3). global_load_lds writes linearly; global SOURCE applies
// the same XOR involution (rule 21); reads apply it (measured 0 bank conflicts).
// Iteration i computes tiles t=2i (phases 1-4, ks-major) and t+1 (phases 5-8).
// Per phase: {8 ds_read (guaranteed by prev closing barrier) | stage 1 slice-pair
//  -> barrier -> lgkmcnt(0) -> setprio(1) 16 MFMA setprio(0) -> [vmcnt(8) even
//  phases] -> barrier}.  Stage->read distance = 6 phases; 12 loads peak in
//  flight; vmcnt(8) retires exactly the slice the NEXT phase reads.
__global__ __launch_bounds__(512, 2) void k_gemm(const unsigned short* __restrict__ Ab,
                                                 const unsigned short* __restrict__ Wb,
                                                 const float* __restrict__ bias,
                                                 float2* __restrict__ Pml) {
    extern __shared__ unsigned short lds[];        // 128 KiB dynamic
    unsigned short* As = lds;                      // [2][2][SLICE_SH]
    unsigned short* Bs = lds + 4 * SLICE_SH;       // [2][2][SLICE_SH]

    const int tid  = threadIdx.x;
    const int wave = tid >> 6, lane = tid & 63;
    const int q    = lane & 15, g = lane >> 4;
    const int wr   = wave >> 2;        // 0..1  (M half: 128 rows)
    const int wc   = wave & 3;         // 0..3  (N quarter: 64 cols)

    // Bijective XCD swizzle: nwg = 16*197 = 3152, 3152 % 8 == 0.
    const int bid0 = (int)blockIdx.x;
    const int bid  = (bid0 & 7) * (NTM * NTN / 8) + (bid0 >> 3);
    const int tm   = bid & 15;         // M fastest: consecutive blocks share W panel
    const int tn   = bid >> 4;
    const size_t arow0 = (size_t)tm * 256;
    const size_t brow0 = (size_t)tn * 256;

    f32x4 acc[8][4];
    const f32x4 zf = {0.f, 0.f, 0.f, 0.f};
#pragma unroll
    for (int i = 0; i < 8; ++i)
#pragma unroll
        for (int j = 0; j < 4; ++j) acc[i][j] = zf;

    // stage K-slice s of tile kt (A and B): 4 loads/lane, buf = kt&1
    auto stage_slice = [&](int kt, int s) {
        const int bufIdx = kt & 1;
        unsigned short* LA = As + (bufIdx * 2 + s) * SLICE_SH;
        unsigned short* LB = Bs + (bufIdx * 2 + s) * SLICE_SH;
#pragma unroll
        for (int j = 0; j < 2; ++j) {
            const int ci  = j * 512 + tid;                 // this lane's 16B chunk
            const int row = ((ci >> 3) << 1) + ((ci >> 2) & 1);
            const int cs  = (ci & 3) ^ ((ci >> 3) & 3);    // pre-swizzled source slot
            const size_t goff = (size_t)kt * 64 + s * 32 + cs * 8;
            const size_t ldst = (size_t)(j * 512 + wave * 64) * 8;
            gload_lds16(Ab + (arow0 + row) * DDIM + goff, LA + ldst);
            gload_lds16(Wb + (brow0 + row) * DDIM + goff, LB + ldst);
        }
    };

    // read one MFMA fragment (row, k-chunk g) from slice base SL
    auto lds_frag = [&](const unsigned short* SL, int row) -> bf16x8 {
        const int line = row >> 1;
        const int p    = ((row & 1) << 2) + (g ^ (line & 3));
        return *(const bf16x8*)(SL + line * 64 + p * 8);
    };

    // one phase. bt: buffer of the tile being READ. vm: -1 none / 8 / 4 / 0.
    auto phase = [&](int bt, int mh, int ks, int stKt, int stS, int vm) {
        const unsigned short* SA = As + (bt * 2 + ks) * SLICE_SH;
        const unsigned short* SB = Bs + (bt * 2 + ks) * SLICE_SH;
        bf16x8 af[4], bfr[4];
#pragma unroll
        for (int fi = 0; fi < 4; ++fi)
            af[fi] = lds_frag(SA, wr * 128 + mh * 64 + fi * 16 + q);
#pragma unroll
        for (int fj = 0; fj < 4; ++fj)
            bfr[fj] = lds_frag(SB, wc * 64 + fj * 16 + q);
        if (stKt >= 0) stage_slice(stKt, stS);
        __builtin_amdgcn_sched_barrier(0);
        __builtin_amdgcn_s_barrier();                       // opening
        asm volatile("s_waitcnt lgkmcnt(0)" ::: "memory");
        __builtin_amdgcn_sched_barrier(0);
        __builtin_amdgcn_s_setprio(1);
#pragma unroll
        for (int fi = 0; fi < 4; ++fi)
#pragma unroll
            for (int fj = 0; fj < 4; ++fj)
                acc[mh * 4 + fi][fj] = __builtin_amdgcn_mfma_f32_16x16x32_bf16(
                    af[fi], bfr[fj], acc[mh * 4 + fi][fj], 0, 0, 0);
        __builtin_amdgcn_s_setprio(0);
        __builtin_amdgcn_sched_barrier(0);
        if (vm == 8)      { asm volatile("s_waitcnt vmcnt(8)" ::: "memory"); __builtin_amdgcn_sched_barrier(0); }
        else if (vm == 4) { asm volatile("s_waitcnt vmcnt(4)" ::: "memory"); __builtin_amdgcn_sched_barrier(0); }
        else if (vm == 0) { asm volatile("s_waitcnt vmcnt(0)" ::: "memory"); __builtin_amdgcn_sched_barrier(0); }
        __builtin_amdgcn_s_barrier();                       // closing
    };

    // prologue: queue = {0.s0, 0.s1, 1.s0}; retire 0.s0 -> vmcnt(8)
    stage_slice(0, 0);
    stage_slice(0, 1);
    stage_slice(1, 0);
    asm volatile("s_waitcnt vmcnt(8)" ::: "memory");
    __builtin_amdgcn_sched_barrier(0);
    __builtin_amdgcn_s_barrier();

#pragma unroll 1
    for (int i = 0; i < 7; ++i) {              // tiles 0..13
        const int t = 2 * i;
        phase(0, 0, 0, t + 1, 1, -1);          // P1: stage (t+1).s1
        phase(0, 1, 0, -1, 0, 8);              // P2: retire (t).s1
        phase(0, 0, 1, t + 2, 0, -1);          // P3: stage (t+2).s0
        phase(0, 1, 1, -1, 0, 8);              // P4: retire (t+1).s0
        phase(1, 0, 0, t + 2, 1, -1);          // P5: stage (t+2).s1
        phase(1, 1, 0, -1, 0, 8);              // P6: retire (t+1).s1
        phase(1, 0, 1, t + 3, 0, -1);          // P7: stage (t+3).s0
        phase(1, 1, 1, -1, 0, 8);              // P8: retire (t+2).s0
    }
    {   // peeled iteration: tiles 14, 15 — stages done except 15.s1 at P1
        phase(0, 0, 0, 15, 1, -1);             // P1: stage 15.s1
        phase(0, 1, 0, -1, 0, 8);              // P2: retire 14.s1
        phase(0, 0, 1, -1, 0, -1);             // P3
        phase(0, 1, 1, -1, 0, 4);              // P4: retire 15.s0
        phase(1, 0, 0, -1, 0, -1);             // P5
        phase(1, 1, 0, -1, 0, 0);              // P6: retire 15.s1 (drain)
        phase(1, 0, 1, -1, 0, -1);             // P7
        phase(1, 1, 1, -1, 0, -1);             // P8
    }

    // -------- epilogue: per-row partial (max, sumexp) over this wave's 64 cols
    float bv[4]; int colv[4];
#pragma unroll
    for (int fj = 0; fj < 4; ++fj) {
        const int col = tn * 256 + wc * 64 + fj * 16 + q;
        colv[fj] = col;
        bv[fj] = (col < VDIM) ? bias[col] : 0.f;
    }
#pragma unroll
    for (int mf = 0; mf < 8; ++mf) {
#pragma unroll
        for (int r = 0; r < 4; ++r) {
            float vv[4];
#pragma unroll
            for (int fj = 0; fj < 4; ++fj) {
                const float lv = acc[mf][fj][r] + bv[fj];
                vv[fj] = (colv[fj] < VDIM) ? lv : NEGBIG;
            }
            float m = fmaxf(fmaxf(vv[0], vv[1]), fmaxf(vv[2], vv[3]));
#pragma unroll
            for (int mask = 1; mask < 16; mask <<= 1) m = fmaxf(m, __shfl_xor(m, mask));
            // all-pad chunk: m == NEGBIG, vv-m == 0, s harmless (zeroed in combine)
            float s = __expf(vv[0] - m) + __expf(vv[1] - m) +
                      __expf(vv[2] - m) + __expf(vv[3] - m);
#pragma unroll
            for (int mask = 1; mask < 16; mask <<= 1) s += __shfl_xor(s, mask);
            if (q == ((mf * 4 + r) & 15)) {
                const int rowg = tm * 256 + wr * 128 + mf * 16 + g * 4 + r;
                Pml[(size_t)rowg * NCHUNK + (tn * 4 + wc)] = make_float2(m, s);
            }
        }
    }
}

// ---------------- finalize: per row, combine partials + label logit ---------
__global__ __launch_bounds__(256) void k_finalize(const float2* __restrict__ Pml,
                                                  const float* __restrict__ emb,
                                                  const float* __restrict__ W,
                                                  const float* __restrict__ bias,
                                                  const int* __restrict__ labels,
                                                  float* __restrict__ acc) {
    const int r    = blockIdx.x;          // 0..NROWS-1
    const int tid  = threadIdx.x;
    const int lane = tid & 63, wave = tid >> 6;

    float m = NEGBIG, l = 0.f;
    for (int c = tid; c < NCHUNK; c += 256) {
        const float2 p = Pml[(size_t)r * NCHUNK + c];
        const float mn = fmaxf(m, p.x);
        l = l * __expf(m - mn) + p.y * __expf(p.x - mn);
        m = mn;
    }
#pragma unroll
    for (int mask = 1; mask < 64; mask <<= 1) {
        const float om = __shfl_xor(m, mask);
        const float ol = __shfl_xor(l, mask);
        const float mn = fmaxf(m, om);
        l = l * __expf(m - mn) + ol * __expf(om - mn);
        m = mn;
    }

    // label logit: fp32 dot(emb_row, W[label]) + bias[label]
    const int bb = r / 2047;
    const int s  = r - bb * 2047;
    const int label = labels[bb * SDIM + s + 1];
    const bool valid = (label != IGNORE_IDX);
    const int lab = valid ? label : 0;
    const float* erow = emb + ((size_t)bb * SDIM + s) * DDIM;
    const float* wrow = W + (size_t)lab * DDIM;
    const float4 e  = *(const float4*)(erow + tid * 4);
    const float4 w4 = *(const float4*)(wrow + tid * 4);
    float d = e.x * w4.x + e.y * w4.y + e.z * w4.z + e.w * w4.w;
#pragma unroll
    for (int mask = 1; mask < 64; mask <<= 1) d += __shfl_xor(d, mask);

    __shared__ float sm[4], sl[4], sd[4];
    if (lane == 0) { sm[wave] = m; sl[wave] = l; sd[wave] = d; }
    __syncthreads();
    if (tid == 0) {
        float M = sm[0], L = sl[0];
#pragma unroll
        for (int wv = 1; wv < 4; ++wv) {
            const float mn = fmaxf(M, sm[wv]);
            L = L * __expf(M - mn) + sl[wv] * __expf(sm[wv] - mn);
            M = mn;
        }
        const float dot = sd[0] + sd[1] + sd[2] + sd[3];
        const float lse = M + logf(L);
        const float logit = dot + bias[lab];
        const float ce = valid ? (lse - logit) : 0.f;
        const float pt = __expf(-ce);
        const float w  = valid ? (1.f - pt) : 0.f;   // gamma = 1.0
        atomicAdd(acc + 0, w * ce);
        atomicAdd(acc + 1, w);
    }
}

__global__ void k_final(const float* __restrict__ acc, float* __restrict__ out) {
    out[0] = acc[0] / acc[1];
}

extern "C" void kernel_launch(void* const* d_in, const int* in_sizes, int n_in,
                              void* d_out, int out_size, void* d_ws, size_t ws_size,
                              hipStream_t stream) {
    const float* emb    = (const float*)d_in[0];
    const float* W      = (const float*)d_in[1];
    const float* bias   = (const float*)d_in[2];
    const int*   labels = (const int*)d_in[3];
    // d_in[4] (input_ids) unused

    char* ws = (char*)d_ws;
    const size_t WB = (size_t)VPAD * DDIM * 2;       // 103,284,736
    const size_t AB = (size_t)MPAD * DDIM * 2;       //   8,388,608
    const size_t PB = (size_t)MPAD * NCHUNK * 8;     //  25,821,184
    unsigned short* Wb  = (unsigned short*)ws;
    unsigned short* Ab  = (unsigned short*)(ws + WB);
    float2*         Pml = (float2*)(ws + WB + AB);
    float*          acc = (float*)(ws + WB + AB + PB);

    k_convert_W<<<VPAD, 256, 0, stream>>>(W, Wb, acc);
    k_convert_A<<<MPAD, 256, 0, stream>>>(emb, Ab);
    k_gemm<<<NTM * NTN, 512, 131072, stream>>>(Ab, Wb, bias, Pml);
    k_finalize<<<NROWS, 256, 0, stream>>>(Pml, emb, W, bias, labels, acc);
    k_final<<<1, 1, 0, stream>>>(acc, (float*)d_out);
}

// Round 8
// 834.043 us; speedup vs baseline: 1.1444x; 1.1444x over previous
//
#include <hip/hip_runtime.h>
#include <hip/hip_bf16.h>
#include <cstdint>

// Problem constants
#define SDIM   2048
#define DDIM   1024
#define VDIM   50257
#define VPAD   50432          // 197 * 256
#define NROWS  4094           // B*(S-1) = 2*2047
#define MPAD   4096
#define NTM    16             // M tiles of 256
#define NTN    197            // N tiles of 256
#define NCHUNK (NTN * 4)      // 788 column chunks of 64
#define NKT    32             // 1024 / 32  (BK = 32)
#define IGNORE_IDX (-100)
// Finite "minus infinity": avoids exp(-inf - -inf) = NaN on all-padding chunks.
#define NEGBIG (-3.0e38f)
#define SLICE_SH 8192         // one K-tile slice: 256 rows x 32 cols bf16 = 16KB

typedef __bf16 bf16x8 __attribute__((ext_vector_type(8)));
typedef float  f32x4  __attribute__((ext_vector_type(4)));

__device__ static inline unsigned short f2bf(float f) {
    union { float f; uint32_t u; } v; v.f = f;
    uint32_t u = v.u;
    return (unsigned short)((u + 0x7FFFu + ((u >> 16) & 1u)) >> 16);  // RNE
}

// global -> LDS direct (16B per lane). LDS dest must be wave-uniform base + lane*16.
__device__ static inline void gload_lds16(const void* g, void* l) {
    __builtin_amdgcn_global_load_lds(
        (const __attribute__((address_space(1))) unsigned int*)(g),
        (__attribute__((address_space(3))) unsigned int*)(l),
        16, 0, 0);
}

// ---------------- convert W (fp32 [V,D]) -> bf16 [VPAD,D], pad rows zero ----
__global__ __launch_bounds__(256) void k_convert_W(const float* __restrict__ W,
                                                   unsigned short* __restrict__ Wb,
                                                   float* __restrict__ acc) {
    if (blockIdx.x == 0 && threadIdx.x < 128) acc[threadIdx.x] = 0.f;  // zero buckets
    const int row = blockIdx.x;            // grid = VPAD
    const int c4  = threadIdx.x << 2;      // 256 threads * 4 = 1024 = D
    ushort4 o;
    if (row < VDIM) {
        const float4 f = *(const float4*)(W + (size_t)row * DDIM + c4);
        o.x = f2bf(f.x); o.y = f2bf(f.y); o.z = f2bf(f.z); o.w = f2bf(f.w);
    } else {
        o.x = o.y = o.z = o.w = 0;
    }
    *(ushort4*)(Wb + (size_t)row * DDIM + c4) = o;
}

// --------- pack shifted embeddings: row r<4094 -> emb[b= r/2047, s= r%2047] ---
__global__ __launch_bounds__(256) void k_convert_A(const float* __restrict__ emb,
                                                   unsigned short* __restrict__ Ab) {
    const int row = blockIdx.x;            // grid = MPAD
    const int c4  = threadIdx.x << 2;
    ushort4 o; o.x = o.y = o.z = o.w = 0;
    if (row < NROWS) {
        const int bb = row / 2047;
        const int s  = row - bb * 2047;
        const float4 f = *(const float4*)(emb + ((size_t)bb * SDIM + s) * DDIM + c4);
        o.x = f2bf(f.x); o.y = f2bf(f.y); o.z = f2bf(f.z); o.w = f2bf(f.w);
    }
    *(ushort4*)(Ab + (size_t)row * DDIM + c4) = o;
}

// ---------------- GEMM 256x256 tile, BK=32, 8 waves, minimal-sync pipeline --
// LDS: per matrix [4 tile-bufs][256 rows][32 cols] bf16; tile t -> buf t&3.
// Slice layout: [128 lines][8 chunks(16B)]; chunk p at line L holds row=2L+(p>>2),
// col-slot cs=(p&3)^(L&3). global_load_lds writes linearly; global SOURCE applies
// the same XOR involution; reads apply it (measured 0 bank conflicts, r5-r7).
// Per tile: 2 phases (mh0: 8 ds_read + stage + 16 MFMA; mh1: 4 ds_read + 16 MFMA
// with B-frags reused), then ONE counted vmcnt(4) + ONE s_barrier.
// Ledger (4 loads/wave per stage): prologue stages t0,t1, vmcnt(4) retires t0.
// Tile t P1 stages t+2 (outstanding 8); vmcnt(4) after tile-t phases retires t+1
// (read next); tile t+1 P1 stages t+3; vmcnt(4) retires t+2. Stage->retire = 3
// phases (~2000 cyc). Stage-write hazard: buf (t+2)&3 last read in tile t-2,
// fenced by the barrier after tile t-1... (two pub barriers back). No opening
// barriers; compiler manages lgkmcnt for plain LDS reads (m97-verified).
__global__ __launch_bounds__(512, 2) void k_gemm(const unsigned short* __restrict__ Ab,
                                                 const unsigned short* __restrict__ Wb,
                                                 const float* __restrict__ bias,
                                                 float2* __restrict__ Pml) {
    extern __shared__ unsigned short lds[];        // 128 KiB dynamic
    unsigned short* As = lds;                      // [4][SLICE_SH]
    unsigned short* Bs = lds + 4 * SLICE_SH;       // [4][SLICE_SH]

    const int tid  = threadIdx.x;
    const int wave = tid >> 6, lane = tid & 63;
    const int q    = lane & 15, g = lane >> 4;
    const int wr   = wave >> 2;        // 0..1  (M half: 128 rows)
    const int wc   = wave & 3;         // 0..3  (N quarter: 64 cols)

    // Bijective XCD swizzle: nwg = 16*197 = 3152, 3152 % 8 == 0.
    const int bid0 = (int)blockIdx.x;
    const int bid  = (bid0 & 7) * (NTM * NTN / 8) + (bid0 >> 3);
    const int tm   = bid & 15;         // M fastest: consecutive blocks share W panel
    const int tn   = bid >> 4;
    const size_t arow0 = (size_t)tm * 256;
    const size_t brow0 = (size_t)tn * 256;

    f32x4 acc[8][4];
    const f32x4 zf = {0.f, 0.f, 0.f, 0.f};
#pragma unroll
    for (int i = 0; i < 8; ++i)
#pragma unroll
        for (int j = 0; j < 4; ++j) acc[i][j] = zf;

    // stage K-tile kt (A and B): 4 loads/lane into buf kt&3
    auto stage = [&](int kt) {
        const int b = kt & 3;
        unsigned short* LA = As + b * SLICE_SH;
        unsigned short* LB = Bs + b * SLICE_SH;
#pragma unroll
        for (int j = 0; j < 2; ++j) {
            const int ci  = j * 512 + tid;                 // this lane's 16B chunk
            const int row = ((ci >> 3) << 1) + ((ci >> 2) & 1);
            const int cs  = (ci & 3) ^ ((ci >> 3) & 3);    // pre-swizzled source slot
            const size_t goff = (size_t)kt * 32 + cs * 8;
            const size_t ldst = (size_t)(j * 512 + wave * 64) * 8;
            gload_lds16(Ab + (arow0 + row) * DDIM + goff, LA + ldst);
            gload_lds16(Wb + (brow0 + row) * DDIM + goff, LB + ldst);
        }
    };

    // read one MFMA fragment (row, k-chunk g) from slice base SL
    auto lds_frag = [&](const unsigned short* SL, int row) -> bf16x8 {
        const int line = row >> 1;
        const int p    = ((row & 1) << 2) + (g ^ (line & 3));
        return *(const bf16x8*)(SL + line * 64 + p * 8);
    };

    // compute one tile: 2 phases; stKt staged during phase 0 (-1 = none)
    auto tile = [&](int t, int stKt) {
        const unsigned short* SA = As + (t & 3) * SLICE_SH;
        const unsigned short* SB = Bs + (t & 3) * SLICE_SH;
        bf16x8 af[4], bfr[4];
        // phase mh0
#pragma unroll
        for (int fi = 0; fi < 4; ++fi)
            af[fi] = lds_frag(SA, wr * 128 + fi * 16 + q);
#pragma unroll
        for (int fj = 0; fj < 4; ++fj)
            bfr[fj] = lds_frag(SB, wc * 64 + fj * 16 + q);
        if (stKt >= 0) stage(stKt);
        __builtin_amdgcn_s_setprio(1);
#pragma unroll
        for (int fi = 0; fi < 4; ++fi)
#pragma unroll
            for (int fj = 0; fj < 4; ++fj)
                acc[fi][fj] = __builtin_amdgcn_mfma_f32_16x16x32_bf16(
                    af[fi], bfr[fj], acc[fi][fj], 0, 0, 0);
        __builtin_amdgcn_s_setprio(0);
        // phase mh1 (reuse bfr)
#pragma unroll
        for (int fi = 0; fi < 4; ++fi)
            af[fi] = lds_frag(SA, wr * 128 + 64 + fi * 16 + q);
        __builtin_amdgcn_s_setprio(1);
#pragma unroll
        for (int fi = 0; fi < 4; ++fi)
#pragma unroll
            for (int fj = 0; fj < 4; ++fj)
                acc[4 + fi][fj] = __builtin_amdgcn_mfma_f32_16x16x32_bf16(
                    af[fi], bfr[fj], acc[4 + fi][fj], 0, 0, 0);
        __builtin_amdgcn_s_setprio(0);
    };

    // prologue: stage tiles 0,1 (8 loads); retire tile 0; publish
    stage(0);
    stage(1);
    asm volatile("s_waitcnt vmcnt(4)" ::: "memory");
    __builtin_amdgcn_s_barrier();

#pragma unroll 2
    for (int i = 0; i < NKT / 2; ++i) {
        const int t = 2 * i;
        tile(t, (t + 2 < NKT) ? (t + 2) : -1);
        if (i == NKT / 2 - 1) { asm volatile("s_waitcnt vmcnt(0)" ::: "memory"); }
        else                  { asm volatile("s_waitcnt vmcnt(4)" ::: "memory"); }
        __builtin_amdgcn_s_barrier();                 // publish tile t+1
        tile(t + 1, (t + 3 < NKT) ? (t + 3) : -1);
        if (i < NKT / 2 - 1) {
            asm volatile("s_waitcnt vmcnt(4)" ::: "memory");
            __builtin_amdgcn_s_barrier();             // publish tile t+2
        }
    }

    // -------- epilogue: per-row partial (max, sumexp) over this wave's 64 cols
    float bv[4]; int colv[4];
#pragma unroll
    for (int fj = 0; fj < 4; ++fj) {
        const int col = tn * 256 + wc * 64 + fj * 16 + q;
        colv[fj] = col;
        bv[fj] = (col < VDIM) ? bias[col] : 0.f;
    }
#pragma unroll
    for (int mf = 0; mf < 8; ++mf) {
#pragma unroll
        for (int r = 0; r < 4; ++r) {
            float vv[4];
#pragma unroll
            for (int fj = 0; fj < 4; ++fj) {
                const float lv = acc[mf][fj][r] + bv[fj];
                vv[fj] = (colv[fj] < VDIM) ? lv : NEGBIG;
            }
            float m = fmaxf(fmaxf(vv[0], vv[1]), fmaxf(vv[2], vv[3]));
#pragma unroll
            for (int mask = 1; mask < 16; mask <<= 1) m = fmaxf(m, __shfl_xor(m, mask));
            // all-pad chunk: m == NEGBIG, vv-m == 0, s harmless (zeroed in combine)
            float s = __expf(vv[0] - m) + __expf(vv[1] - m) +
                      __expf(vv[2] - m) + __expf(vv[3] - m);
#pragma unroll
            for (int mask = 1; mask < 16; mask <<= 1) s += __shfl_xor(s, mask);
            if (q == ((mf * 4 + r) & 15)) {
                const int rowg = tm * 256 + wr * 128 + mf * 16 + g * 4 + r;
                Pml[(size_t)rowg * NCHUNK + (tn * 4 + wc)] = make_float2(m, s);
            }
        }
    }
}

// ---------------- finalize: per row, combine partials + label logit ---------
__global__ __launch_bounds__(256) void k_finalize(const float2* __restrict__ Pml,
                                                  const float* __restrict__ emb,
                                                  const float* __restrict__ W,
                                                  const float* __restrict__ bias,
                                                  const int* __restrict__ labels,
                                                  float* __restrict__ acc) {
    const int r    = blockIdx.x;          // 0..NROWS-1
    const int tid  = threadIdx.x;
    const int lane = tid & 63, wave = tid >> 6;

    float m = NEGBIG, l = 0.f;
    for (int c = tid; c < NCHUNK; c += 256) {
        const float2 p = Pml[(size_t)r * NCHUNK + c];
        const float mn = fmaxf(m, p.x);
        l = l * __expf(m - mn) + p.y * __expf(p.x - mn);
        m = mn;
    }
#pragma unroll
    for (int mask = 1; mask < 64; mask <<= 1) {
        const float om = __shfl_xor(m, mask);
        const float ol = __shfl_xor(l, mask);
        const float mn = fmaxf(m, om);
        l = l * __expf(m - mn) + ol * __expf(om - mn);
        m = mn;
    }

    // label logit: fp32 dot(emb_row, W[label]) + bias[label]
    const int bb = r / 2047;
    const int s  = r - bb * 2047;
    const int label = labels[bb * SDIM + s + 1];
    const bool valid = (label != IGNORE_IDX);
    const int lab = valid ? label : 0;
    const float* erow = emb + ((size_t)bb * SDIM + s) * DDIM;
    const float* wrow = W + (size_t)lab * DDIM;
    const float4 e  = *(const float4*)(erow + tid * 4);
    const float4 w4 = *(const float4*)(wrow + tid * 4);
    float d = e.x * w4.x + e.y * w4.y + e.z * w4.z + e.w * w4.w;
#pragma unroll
    for (int mask = 1; mask < 64; mask <<= 1) d += __shfl_xor(d, mask);

    __shared__ float sm[4], sl[4], sd[4];
    if (lane == 0) { sm[wave] = m; sl[wave] = l; sd[wave] = d; }
    __syncthreads();
    if (tid == 0) {
        float M = sm[0], L = sl[0];
#pragma unroll
        for (int wv = 1; wv < 4; ++wv) {
            const float mn = fmaxf(M, sm[wv]);
            L = L * __expf(M - mn) + sl[wv] * __expf(sm[wv] - mn);
            M = mn;
        }
        const float dot = sd[0] + sd[1] + sd[2] + sd[3];
        const float lse = M + logf(L);
        const float logit = dot + bias[lab];
        const float ce = valid ? (lse - logit) : 0.f;
        const float pt = __expf(-ce);
        const float w  = valid ? (1.f - pt) : 0.f;   // gamma = 1.0
        const int bkt = blockIdx.x & 63;             // bucketed: 64x less contention
        atomicAdd(acc + bkt, w * ce);
        atomicAdd(acc + 64 + bkt, w);
    }
}

__global__ void k_final(const float* __restrict__ acc, float* __restrict__ out) {
    float num = 0.f, den = 0.f;
#pragma unroll
    for (int i = 0; i < 64; ++i) { num += acc[i]; den += acc[64 + i]; }
    out[0] = num / den;
}

extern "C" void kernel_launch(void* const* d_in, const int* in_sizes, int n_in,
                              void* d_out, int out_size, void* d_ws, size_t ws_size,
                              hipStream_t stream) {
    const float* emb    = (const float*)d_in[0];
    const float* W      = (const float*)d_in[1];
    const float* bias   = (const float*)d_in[2];
    const int*   labels = (const int*)d_in[3];
    // d_in[4] (input_ids) unused

    char* ws = (char*)d_ws;
    const size_t WB = (size_t)VPAD * DDIM * 2;       // 103,284,736
    const size_t AB = (size_t)MPAD * DDIM * 2;       //   8,388,608
    const size_t PB = (size_t)MPAD * NCHUNK * 8;     //  25,821,184
    unsigned short* Wb  = (unsigned short*)ws;
    unsigned short* Ab  = (unsigned short*)(ws + WB);
    float2*         Pml = (float2*)(ws + WB + AB);
    float*          acc = (float*)(ws + WB + AB + PB);

    k_convert_W<<<VPAD, 256, 0, stream>>>(W, Wb, acc);
    k_convert_A<<<MPAD, 256, 0, stream>>>(emb, Ab);
    k_gemm<<<NTM * NTN, 512, 131072, stream>>>(Ab, Wb, bias, Pml);
    k_finalize<<<NROWS, 256, 0, stream>>>(Pml, emb, W, bias, labels, acc);
    k_final<<<1, 1, 0, stream>>>(acc, (float*)d_out);
}